// Round 4
// baseline (356.308 us; speedup 1.0000x reference)
//
#include <hip/hip_runtime.h>
#include <hip/hip_bf16.h>

// SRU cell, fp32 in / fp32 out (internal bf16 MFMA GEMM).
// u = x@W; then L-sequential scan parallel over B*d.
// L=1024, B=32, d=512. M=32768, K=512, N=1536.
// ws: Wt (bf16 [N][K], 1.5MB) | u (bf16 [M][N], 96MB)

typedef __attribute__((ext_vector_type(8))) __bf16 bf16x8;
typedef __attribute__((ext_vector_type(4))) __bf16 bf16x4;
typedef __attribute__((ext_vector_type(4))) float floatx4;

#define GK 512
#define GN 1536

#define WAITV(N) asm volatile("s_waitcnt vmcnt(" #N ")" ::: "memory")
#define FENCE() asm volatile("" ::: "memory")

// ---- weight transpose: W[K][N] fp32 -> Wt[N][K] bf16, LDS-tiled -------------
__global__ __launch_bounds__(256) void cvt_w(const float* __restrict__ w,
                                             __bf16* __restrict__ wt) {
  __shared__ float tile[64][65];
  const int bk = blockIdx.x;  // 8 tiles along K
  const int bn = blockIdx.y;  // 24 tiles along N
  const int t = threadIdx.x;
  const int tr = t >> 6;   // 0..3
  const int tc = t & 63;   // 0..63
#pragma unroll
  for (int i = 0; i < 16; ++i) {
    int kl = i * 4 + tr;
    tile[kl][tc] = w[(size_t)(bk * 64 + kl) * GN + bn * 64 + tc];
  }
  __syncthreads();
#pragma unroll
  for (int i = 0; i < 16; ++i) {
    int nl = i * 4 + tr;
    wt[(size_t)(bn * 64 + nl) * GK + bk * 64 + tc] = (__bf16)tile[tc][nl];
  }
}

// ---- GEMM: C[M][N] = A_f32[M][K] * Wt[N][K]^T, bf16 MFMA, bf16 out -----------
// m97-faithful structure: 128x128 tile, BK=64, SINGLE-buffered 32KB LDS,
// 2 barriers per K-step with full vmcnt(0) drain; latency hidden by TLP
// (3 blocks/CU all-resident, m114 overlap) instead of intra-block pipelining
// (R2/R3 depth-3 at 2 blocks/CU measured null). Persistent jobs: grid 768,
// each block runs 4 m-tiles at FIXED n0 (Wt panel stays L2-hot), 32 K-steps
// per block so the prologue is paid once. Same-XCD blocks share the n-panel
// and a contiguous m-range (~1MB active A per XCD L2). XOR swizzle
// (chunk ^= row&7) keeps ds_read_b128 at free 2-way bank aliasing.
__global__ __launch_bounds__(256, 3) void gemm_kernel(const float* __restrict__ A,
                                                      const __bf16* __restrict__ Bt,
                                                      __bf16* __restrict__ C) {
  __shared__ __attribute__((aligned(16))) __bf16 As[128 * 64];
  __shared__ __attribute__((aligned(16))) __bf16 Bs[128 * 64];
  // job map: id -> (xcd, q); n varies fastest within an XCD so the 12 blocks
  // sharing an m-range are launched adjacently.
  const int id = blockIdx.x;       // [0,768)
  const int xcd = id & 7;
  const int q = id >> 3;           // [0,96)
  const int n_idx = q % 12;
  const int mgl = q / 12;          // [0,8)
  const int n0 = n_idx * 128;
  const int mbase = (xcd * 32 + mgl * 4) * 128;  // 4 consecutive m-tiles

  const int t = threadIdx.x;
  const int wave = t >> 6, lane = t & 63;
  const int quad = lane >> 4, l16 = lane & 15;
  const int wm = (wave >> 1) * 64, wn = (wave & 1) * 64;

  const int ar = t >> 4;         // A row group (0..15)
  const int ak = (t & 15) * 4;   // A k-chunk (float4) within BK
  const int ac = (t & 15) >> 1;  // 16B-chunk within LDS row
  const int ah = t & 1;          // 8B half within chunk
  float4 areg[8];

  for (int r = 0; r < 4; ++r) {
    const int m0 = mbase + r * 128;
    floatx4 acc[4][4] = {};

    for (int k = 0; k < 8; ++k) {
      const int k0 = k * 64;
      // stage A: 8 coalesced float4 loads into regs
#pragma unroll
      for (int qq = 0; qq < 8; ++qq)
        areg[qq] = *(const float4*)(A + (size_t)(m0 + qq * 16 + ar) * GK + k0 + ak);
      // stage B: 4 async global_load_lds, source pre-swizzled, LDS linear
#pragma unroll
      for (int qq = 0; qq < 4; ++qq) {
        int rb = wave * 4 + qq;
        int n = rb * 8 + (lane >> 3);
        int cB = lane & 7;
        const __bf16* src = Bt + (size_t)(n0 + n) * GK + k0 + ((cB ^ (n & 7)) * 8);
        __builtin_amdgcn_global_load_lds(
            (const __attribute__((address_space(1))) void*)src,
            (__attribute__((address_space(3))) void*)(Bs + rb * 512), 16, 0, 0);
      }
      WAITV(4);  // A regs landed (also drains any prior-job epilogue stores)
#pragma unroll
      for (int qq = 0; qq < 8; ++qq) {
        int rr = qq * 16 + ar;
        float4 v = areg[qq];
        bf16x4 o = {(__bf16)v.x, (__bf16)v.y, (__bf16)v.z, (__bf16)v.w};
        *(bf16x4*)(As + rr * 64 + (ac ^ (rr & 7)) * 8 + ah * 4) = o;
      }
      WAITV(0);  // B landed in LDS
      asm volatile("s_waitcnt lgkmcnt(0)" ::: "memory");
      __builtin_amdgcn_s_barrier();  // tile ready
      FENCE();
      // compute: 2 k-windows of 32
#pragma unroll
      for (int ks = 0; ks < 2; ++ks) {
        bf16x8 af[4], bfr[4];
#pragma unroll
        for (int qq = 0; qq < 4; ++qq) {
          int m = wm + qq * 16 + l16;
          af[qq] = *(const bf16x8*)(As + m * 64 + (((ks * 4 + quad) ^ (m & 7)) * 8));
          int n = wn + qq * 16 + l16;
          bfr[qq] = *(const bf16x8*)(Bs + n * 64 + (((ks * 4 + quad) ^ (n & 7)) * 8));
        }
#pragma unroll
        for (int tm = 0; tm < 4; ++tm)
#pragma unroll
          for (int tn = 0; tn < 4; ++tn)
            acc[tm][tn] = __builtin_amdgcn_mfma_f32_16x16x32_bf16(
                af[tm], bfr[tn], acc[tm][tn], 0, 0, 0);
      }
      FENCE();
      __builtin_amdgcn_s_barrier();  // all waves done reading tile
      FENCE();
    }

    // epilogue for this job (fire-and-forget; drained by next job's WAITV)
    // C/D layout col=lane&15, row=quad*4+reg (m89-verified)
#pragma unroll
    for (int tm = 0; tm < 4; ++tm)
#pragma unroll
      for (int tn = 0; tn < 4; ++tn)
#pragma unroll
        for (int i = 0; i < 4; ++i) {
          int m = m0 + wm + tm * 16 + quad * 4 + i;
          int n = n0 + wn + tn * 16 + l16;
          C[(size_t)m * GN + n] = (__bf16)acc[tm][tn][i];
        }
  }
}

// ---- SRU scan: producer/consumer; u-only 8-deep LDS ring; x direct-to-reg ---
// 256 blocks x 128 thr. Block g owns 64 channels: b=g>>3, j=j0+lane.
// Producer (wave1) stages ONLY u (6 KB/stage): in-flight 7 stages = 42 KB/blk
// -> chip queue delay ~1.7us < 7-stage compute lookahead ~2.8us (was razor-
// edge at 10KB stages). Consumer (wave0) prefetches x fp32 straight into
// registers one stage ahead (16 coalesced loads, ping-pong banks); its vmcnt
// counts [xload(s), stores(s-1), xload(s+1)] in order, so WAITV(32) = xload(s)
// landed (WAITV(16) at s=0/63). No full drains anywhere.
__global__ __launch_bounds__(128, 1) void scan_kernel(
    const __bf16* __restrict__ u, const float* __restrict__ x,
    const float* __restrict__ wc, const float* __restrict__ bias,
    const float* __restrict__ c0, float* __restrict__ out) {
  __shared__ __attribute__((aligned(16))) unsigned char ring[8][6144];
  const int g = blockIdx.x;
  const int b = g >> 3;
  const int j0 = (g & 7) * 64;
  const int wave = threadIdx.x >> 6;
  const int lane = threadIdx.x & 63;
  const int ob = b * 512 + j0 + lane;  // this lane's channel (consumer)

  if (wave == 1) {
    // producer: per-lane time-invariant element offsets (u only)
    int pre_u[6];
#pragma unroll
    for (int r = 0; r < 6; ++r) {
      int seg = r * 8 + (lane >> 3);  // seg = i*3 + qc
      int i = seg / 3;
      int qc = seg - i * 3;
      pre_u[r] = i * 49152 + b * 1536 + qc * 512 + j0 + (lane & 7) * 8;
    }
#define ISSUE(st)                                                              \
  {                                                                            \
    unsigned char* base = ring[(st) & 7];                                      \
    size_t tu = (size_t)(st) * 16 * 49152;                                     \
    _Pragma("unroll") for (int r = 0; r < 6; ++r)                              \
        __builtin_amdgcn_global_load_lds(                                      \
            (const __attribute__((address_space(1))) void*)(u + tu + pre_u[r]),\
            (__attribute__((address_space(3))) void*)(base + r * 1024), 16, 0, \
            0);                                                                \
  }
    ISSUE(0); ISSUE(1); ISSUE(2); ISSUE(3); ISSUE(4); ISSUE(5); ISSUE(6);
    for (int s = 0; s < 64; ++s) {
      // retire stage s (oldest 6 loads); 6*(stages in flight - 1) remain
      if (s <= 57) {
        WAITV(36);
      } else if (s == 58) {
        WAITV(30);
      } else if (s == 59) {
        WAITV(24);
      } else if (s == 60) {
        WAITV(18);
      } else if (s == 61) {
        WAITV(12);
      } else if (s == 62) {
        WAITV(6);
      } else {
        WAITV(0);
      }
      __builtin_amdgcn_s_barrier();  // release stage s to consumer
      FENCE();
      if (s + 7 < 64) ISSUE(s + 7);  // slot (s-1)&7: consumer already done
    }
#undef ISSUE
  } else {
    // consumer
    const float vf = wc[j0 + lane], vr = wc[512 + j0 + lane];
    const float bfv = bias[j0 + lane], brv = bias[512 + j0 + lane];
    float c = c0[ob];
    float* op = out + ob;
    float xra[16], xrb[16];
    // prologue: x for stage 0 -> bank A
#pragma unroll
    for (int i = 0; i < 16; ++i) xra[i] = x[(size_t)i * 16384 + ob];

#define CONS_STAGE(S, CUR, NXT)                                             \
  {                                                                         \
    __builtin_amdgcn_s_barrier(); /* u[stage S] ready in LDS */             \
    FENCE();                                                                \
    if ((S) + 1 < 64) {                                                     \
      _Pragma("unroll") for (int i = 0; i < 16; ++i) NXT[i] =               \
          x[(size_t)(((S) + 1) * 16 + i) * 16384 + ob];                     \
    }                                                                       \
    if ((S) == 0 || (S) == 63) { WAITV(16); } else { WAITV(32); }           \
    const unsigned char* base = ring[(S) & 7];                              \
    _Pragma("unroll") for (int i = 0; i < 16; ++i) {                        \
      float u0 = (float)*(const __bf16*)(base + i * 384 + lane * 2);        \
      float u1 = (float)*(const __bf16*)(base + i * 384 + 128 + lane * 2);  \
      float u2 = (float)*(const __bf16*)(base + i * 384 + 256 + lane * 2);  \
      float a1 = __builtin_fmaf(vf, c, u1 + bfv);                           \
      float f = __builtin_amdgcn_rcpf(1.f + __expf(-a1));                   \
      c = __builtin_fmaf(f, c - u0, u0);                                    \
      float a2 = __builtin_fmaf(vr, c, u2 + brv);                           \
      float rg = __builtin_amdgcn_rcpf(1.f + __expf(-a2));                  \
      float tt = __expf(-2.f * __builtin_fabsf(c));                         \
      float gg = (1.f - tt) * __builtin_amdgcn_rcpf(1.f + tt);              \
      gg = __builtin_copysignf(gg, c);                                      \
      float xs = CUR[i] * 1.7320508075688772f;                              \
      float h = __builtin_fmaf(rg, gg - xs, xs);                            \
      op[(size_t)((S) * 16 + i) * 16384] = h;                               \
    }                                                                       \
    FENCE();                                                                \
  }

    for (int sp = 0; sp < 64; sp += 2) {
      CONS_STAGE(sp, xra, xrb);
      CONS_STAGE(sp + 1, xrb, xra);
    }
#undef CONS_STAGE
    out[(size_t)16777216 + ob] = c;  // c_last
  }
}

extern "C" void kernel_launch(void* const* d_in, const int* in_sizes, int n_in,
                              void* d_out, int out_size, void* d_ws, size_t ws_size,
                              hipStream_t stream) {
  const float* x = (const float*)d_in[0];     // (1024,32,512) fp32
  const float* w = (const float*)d_in[1];     // (512,1536)    fp32
  const float* wc = (const float*)d_in[2];    // (1024,)       fp32
  const float* bias = (const float*)d_in[3];  // (1024,)       fp32
  const float* c0 = (const float*)d_in[4];    // (32,512)      fp32
  float* out = (float*)d_out;                 // h (L,B,d) | c_last (B,d)

  char* ws = (char*)d_ws;
  __bf16* wt = (__bf16*)ws;             // 1,572,864 B
  __bf16* u = (__bf16*)(ws + 1572864);  // 100,663,296 B

  cvt_w<<<dim3(8, 24), 256, 0, stream>>>(w, wt);
  gemm_kernel<<<768, 256, 0, stream>>>(x, wt, u);
  scan_kernel<<<256, 128, 0, stream>>>(u, x, wc, bias, c0, out);
}

// Round 5
// 223.366 us; speedup vs baseline: 1.5952x; 1.5952x over previous
//
#include <hip/hip_runtime.h>
#include <hip/hip_bf16.h>

// SRU cell, fully fused: u = x@W computed on-the-fly inside the scan kernel
// (u never materialized). L=1024, B=32, d=512.
// Block = one (b, 64-channel group): 8 waves =
//   waves 0-5: MFMA (each owns 32 output cols; W-slice in 128 VGPRs)
//   wave 6:    x producer (fp32 global -> bf16 swizzled LDS, double-buffered)
//   wave 7:    scan (64 serial chains; consumes u(s-1) while gemm makes u(s))
// One raw s_barrier + lgkmcnt(0) per 16-step stage; no vmcnt drains.
// ws: Wt (bf16 [1536][512], 1.5MB) only.

typedef __attribute__((ext_vector_type(8))) __bf16 bf16x8;
typedef __attribute__((ext_vector_type(4))) __bf16 bf16x4;
typedef __attribute__((ext_vector_type(4))) float floatx4;

#define WAITV(N) asm volatile("s_waitcnt vmcnt(" #N ")" ::: "memory")
#define WAITL() asm volatile("s_waitcnt lgkmcnt(0)" ::: "memory")

#define GK 512
#define GN 1536

// ---- weight transpose: W[K][N] fp32 -> Wt[N][K] bf16, LDS-tiled -------------
__global__ __launch_bounds__(256) void cvt_w(const float* __restrict__ w,
                                             __bf16* __restrict__ wt) {
  __shared__ float tile[64][65];
  const int bk = blockIdx.x;  // 8 tiles along K
  const int bn = blockIdx.y;  // 24 tiles along N
  const int t = threadIdx.x;
  const int tr = t >> 6;   // 0..3
  const int tc = t & 63;   // 0..63
#pragma unroll
  for (int i = 0; i < 16; ++i) {
    int kl = i * 4 + tr;
    tile[kl][tc] = w[(size_t)(bk * 64 + kl) * GN + bn * 64 + tc];
  }
  __syncthreads();
#pragma unroll
  for (int i = 0; i < 16; ++i) {
    int nl = i * 4 + tr;
    wt[(size_t)(bn * 64 + nl) * GK + bk * 64 + tc] = (__bf16)tile[tc][nl];
  }
}

// ---- fused GEMM + scan ------------------------------------------------------
// 256 blocks x 512 threads. XCD-aware mapping (XCD = g&7 round-robin):
// XCD x hosts b in {4x..4x+3} so the 8 blocks sharing a batch read x[b]
// through one L2 (8x reuse L2-served, x HBM-read once).
__global__ __launch_bounds__(512, 2) void fused_kernel(
    const float* __restrict__ x, const __bf16* __restrict__ wt,
    const float* __restrict__ wc, const float* __restrict__ bias,
    const float* __restrict__ c0, float* __restrict__ out) {
  // xbuf: 16 t-rows x 512 k bf16, XOR-swizzled (chunk ^= row&7), double-buf
  // ubuf: 16 t-rows x 192 cols fp32, padded to 201 (breaks quad-stride banks)
  __shared__ __attribute__((aligned(16))) __bf16 xbuf[2][16 * 512];
  __shared__ __attribute__((aligned(16))) float ubuf[2][16][201];
  const int g = blockIdx.x;
  const int b = (g & 7) * 4 + ((g >> 3) & 3);
  const int j0 = (g >> 5) * 64;
  const int wave = threadIdx.x >> 6;
  const int lane = threadIdx.x & 63;
  const int quad = lane >> 4, l16 = lane & 15;

  if (wave < 6) {
    // ---------------- MFMA role ----------------
    const int comp = wave >> 1, hn = wave & 1;     // component 0..2, half 0..1
    const int lnb = comp * 64 + hn * 32;           // local col base in ubuf
    const int nb = comp * 512 + j0 + hn * 32;      // global n base in Wt
    // W-slice resident in registers: breg[ki][nt] = Wt[nb+nt*16+l16][k-window]
    bf16x8 breg[16][2];
#pragma unroll
    for (int ki = 0; ki < 16; ++ki)
#pragma unroll
      for (int nt = 0; nt < 2; ++nt)
        breg[ki][nt] = *(const bf16x8*)(wt + (size_t)(nb + nt * 16 + l16) * GK +
                                        ki * 32 + quad * 8);
    __builtin_amdgcn_s_barrier();  // prime (xbuf[0] ready)
    for (int s = 0; s < 64; ++s) {
      const __bf16* xb = xbuf[s & 1];
      floatx4 acc0 = {}, acc1 = {};
#pragma unroll
      for (int ki = 0; ki < 16; ++ki) {
        bf16x8 af = *(const bf16x8*)(xb + l16 * 512 +
                                     (((4 * ki + quad) ^ (l16 & 7)) * 8));
        acc0 = __builtin_amdgcn_mfma_f32_16x16x32_bf16(af, breg[ki][0], acc0, 0, 0, 0);
        acc1 = __builtin_amdgcn_mfma_f32_16x16x32_bf16(af, breg[ki][1], acc1, 0, 0, 0);
      }
      // D layout: row(t)=quad*4+i, col(n)=l16 (m89-verified)
      float* ub = &ubuf[s & 1][0][0];
#pragma unroll
      for (int i = 0; i < 4; ++i) {
        ub[(quad * 4 + i) * 201 + lnb + l16] = acc0[i];
        ub[(quad * 4 + i) * 201 + lnb + 16 + l16] = acc1[i];
      }
      WAITL();
      __builtin_amdgcn_s_barrier();
    }
  } else if (wave == 6) {
    // ---------------- x producer role ----------------
    const float* xsrc = x + (size_t)b * 512;
    float4 xr[32];
#define XISSUE(BLK)                                                         \
  _Pragma("unroll") for (int v = 0; v < 32; ++v) {                          \
    int r = v >> 1;                                                         \
    int fq = (v & 1) * 64 + lane;                                           \
    xr[v] = *(const float4*)(xsrc + (size_t)((BLK) * 16 + r) * 16384 + fq * 4); \
  }
#define XWRITE(BUF)                                                         \
  _Pragma("unroll") for (int v = 0; v < 32; ++v) {                          \
    int r = v >> 1;                                                         \
    int fq = (v & 1) * 64 + lane;                                           \
    float4 w4 = xr[v];                                                      \
    bf16x4 o = {(__bf16)w4.x, (__bf16)w4.y, (__bf16)w4.z, (__bf16)w4.w};    \
    *(bf16x4*)((__bf16*)xbuf[BUF] + r * 512 + (((fq >> 1) ^ (r & 7)) * 8) + \
               (fq & 1) * 4) = o;                                           \
  }
    XISSUE(0);
    WAITV(0);
    XWRITE(0);
    XISSUE(1);  // stage-ahead: latency hidden under stage 0
    WAITL();
    __builtin_amdgcn_s_barrier();  // prime
    for (int s = 0; s < 64; ++s) {
      if (s + 1 < 64) {
        WAITV(0);            // regs for x-tile s+1 landed (issued last stage)
        XWRITE((s + 1) & 1); // gemm reads xbuf[s&1] concurrently
      }
      if (s + 2 < 64) XISSUE(s + 2);
      WAITL();
      __builtin_amdgcn_s_barrier();
    }
#undef XISSUE
#undef XWRITE
  } else {
    // ---------------- scan role ----------------
    const int ob = b * 512 + j0 + lane;
    const float vf = wc[j0 + lane], vr = wc[512 + j0 + lane];
    const float bfv = bias[j0 + lane], brv = bias[512 + j0 + lane];
    float c = c0[ob];
    float* op = out + ob;
    const float* xs2 = x + ob;
    float xa[16], xb2[16];
#define XLOAD(BANK, BLK)                                                    \
  _Pragma("unroll") for (int i = 0; i < 16; ++i) BANK[i] =                  \
      xs2[(size_t)((BLK) * 16 + i) * 16384];
#define CONSUME(S1, BANK)                                                   \
  {                                                                         \
    const float* ub = &ubuf[(S1) & 1][0][0];                                \
    _Pragma("unroll") for (int i = 0; i < 16; ++i) {                        \
      float u0 = ub[i * 201 + lane];                                        \
      float u1 = ub[i * 201 + 64 + lane];                                   \
      float u2 = ub[i * 201 + 128 + lane];                                  \
      float a1 = __builtin_fmaf(vf, c, u1 + bfv);                           \
      float f = __builtin_amdgcn_rcpf(1.f + __expf(-a1));                   \
      c = __builtin_fmaf(f, c - u0, u0);                                    \
      float a2 = __builtin_fmaf(vr, c, u2 + brv);                           \
      float rg = __builtin_amdgcn_rcpf(1.f + __expf(-a2));                  \
      float tt = __expf(-2.f * __builtin_fabsf(c));                         \
      float gg = (1.f - tt) * __builtin_amdgcn_rcpf(1.f + tt);              \
      gg = __builtin_copysignf(gg, c);                                      \
      float xsc = BANK[i] * 1.7320508075688772f;                            \
      float h = __builtin_fmaf(rg, gg - xsc, xsc);                          \
      op[(size_t)((S1) * 16 + i) * 16384] = h;                              \
    }                                                                       \
  }
    __builtin_amdgcn_s_barrier();  // prime
    // stage 0: issue x(0) only (nothing to consume yet)
    XLOAD(xa, 0);
    __builtin_amdgcn_s_barrier();
    // stages 1..62 in ping-pong pairs; stage s issues XL(s)->bank[s&1],
    // WAITV(16) retires XL(s-1)+stores(s-2), consumes u(s-1)+x(s-1).
    for (int sp = 1; sp < 63; sp += 2) {
      XLOAD(xb2, sp);
      WAITV(16);
      CONSUME(sp - 1, xa);
      __builtin_amdgcn_s_barrier();
      XLOAD(xa, sp + 1);
      WAITV(16);
      CONSUME(sp, xb2);
      __builtin_amdgcn_s_barrier();
    }
    // stage 63
    XLOAD(xb2, 63);
    WAITV(16);
    CONSUME(62, xa);
    __builtin_amdgcn_s_barrier();
    // tail: consume u(63) (written before the last barrier)
    WAITV(16);
    CONSUME(63, xb2);
    out[(size_t)16777216 + ob] = c;  // c_last
#undef XLOAD
#undef CONSUME
  }
}

extern "C" void kernel_launch(void* const* d_in, const int* in_sizes, int n_in,
                              void* d_out, int out_size, void* d_ws, size_t ws_size,
                              hipStream_t stream) {
  const float* x = (const float*)d_in[0];     // (1024,32,512) fp32
  const float* w = (const float*)d_in[1];     // (512,1536)    fp32
  const float* wc = (const float*)d_in[2];    // (1024,)       fp32
  const float* bias = (const float*)d_in[3];  // (1024,)       fp32
  const float* c0 = (const float*)d_in[4];    // (32,512)      fp32
  float* out = (float*)d_out;                 // h (L,B,d) | c_last (B,d)

  char* ws = (char*)d_ws;
  __bf16* wt = (__bf16*)ws;  // 1,572,864 B

  cvt_w<<<dim3(8, 24), 256, 0, stream>>>(w, wt);
  fused_kernel<<<256, 512, 0, stream>>>(x, wt, wc, bias, c0, out);
}

// Round 6
// 204.040 us; speedup vs baseline: 1.7463x; 1.0947x over previous
//
#include <hip/hip_runtime.h>
#include <hip/hip_bf16.h>

// SRU cell, fully fused: u = x@W computed on-the-fly inside the scan kernel
// (u never materialized). L=1024, B=32, d=512.
// Block = one (b, 64-channel group): 8 waves =
//   waves 0-5: MFMA (each owns 32 output cols; W-slice in 128 VGPRs)
//   wave 6:    x producer (fp32 global -> bf16 swizzled LDS, double-buffered)
//   wave 7:    scan (64 serial chains; consumes u(s-1) while gemm makes u(s))
// One raw s_barrier + lgkmcnt(0) per 16-step stage; no vmcnt drains.
// Scan stage is 3-pass (R6): pass0 = u loads + off-chain precompute; pass1 =
// minimal serial c-chain (fma/exp/rcp/fma only, ~62cy/step); pass2 = r/tanh/h
// with full cross-step ILP. (R5 post-mortem: the as-compiled single-pass body
// serialized ~250cy/step, gating the whole kernel at ~5200cy/stage.)
// ws: Wt (bf16 [1536][512], 1.5MB) only.

typedef __attribute__((ext_vector_type(8))) __bf16 bf16x8;
typedef __attribute__((ext_vector_type(4))) __bf16 bf16x4;
typedef __attribute__((ext_vector_type(4))) float floatx4;

#define WAITV(N) asm volatile("s_waitcnt vmcnt(" #N ")" ::: "memory")
#define WAITL() asm volatile("s_waitcnt lgkmcnt(0)" ::: "memory")

#define GK 512
#define GN 1536

// ---- weight transpose: W[K][N] fp32 -> Wt[N][K] bf16, LDS-tiled -------------
__global__ __launch_bounds__(256) void cvt_w(const float* __restrict__ w,
                                             __bf16* __restrict__ wt) {
  __shared__ float tile[64][65];
  const int bk = blockIdx.x;  // 8 tiles along K
  const int bn = blockIdx.y;  // 24 tiles along N
  const int t = threadIdx.x;
  const int tr = t >> 6;   // 0..3
  const int tc = t & 63;   // 0..63
#pragma unroll
  for (int i = 0; i < 16; ++i) {
    int kl = i * 4 + tr;
    tile[kl][tc] = w[(size_t)(bk * 64 + kl) * GN + bn * 64 + tc];
  }
  __syncthreads();
#pragma unroll
  for (int i = 0; i < 16; ++i) {
    int nl = i * 4 + tr;
    wt[(size_t)(bn * 64 + nl) * GK + bk * 64 + tc] = (__bf16)tile[tc][nl];
  }
}

// ---- fused GEMM + scan ------------------------------------------------------
// 256 blocks x 512 threads. XCD-aware mapping (XCD = g&7 round-robin):
// XCD x hosts b in {4x..4x+3} so the 8 blocks sharing a batch read x[b]
// through one L2 (8x reuse L2-served, x HBM-read once).
__global__ __launch_bounds__(512, 2) void fused_kernel(
    const float* __restrict__ x, const __bf16* __restrict__ wt,
    const float* __restrict__ wc, const float* __restrict__ bias,
    const float* __restrict__ c0, float* __restrict__ out) {
  // xbuf: 16 t-rows x 512 k bf16, XOR-swizzled (chunk ^= row&7), double-buf
  // ubuf: 16 t-rows x 192 cols fp32, padded to 201 (breaks quad-stride banks)
  __shared__ __attribute__((aligned(16))) __bf16 xbuf[2][16 * 512];
  __shared__ __attribute__((aligned(16))) float ubuf[2][16][201];
  const int g = blockIdx.x;
  const int b = (g & 7) * 4 + ((g >> 3) & 3);
  const int j0 = (g >> 5) * 64;
  const int wave = threadIdx.x >> 6;
  const int lane = threadIdx.x & 63;
  const int quad = lane >> 4, l16 = lane & 15;

  if (wave < 6) {
    // ---------------- MFMA role ----------------
    const int comp = wave >> 1, hn = wave & 1;     // component 0..2, half 0..1
    const int lnb = comp * 64 + hn * 32;           // local col base in ubuf
    const int nb = comp * 512 + j0 + hn * 32;      // global n base in Wt
    // W-slice resident in registers: breg[ki][nt] = Wt[nb+nt*16+l16][k-window]
    bf16x8 breg[16][2];
#pragma unroll
    for (int ki = 0; ki < 16; ++ki)
#pragma unroll
      for (int nt = 0; nt < 2; ++nt)
        breg[ki][nt] = *(const bf16x8*)(wt + (size_t)(nb + nt * 16 + l16) * GK +
                                        ki * 32 + quad * 8);
    __builtin_amdgcn_s_barrier();  // prime (xbuf[0] ready)
    for (int s = 0; s < 64; ++s) {
      const __bf16* xb = xbuf[s & 1];
      floatx4 acc0 = {}, acc1 = {};
#pragma unroll
      for (int ki = 0; ki < 16; ++ki) {
        bf16x8 af = *(const bf16x8*)(xb + l16 * 512 +
                                     (((4 * ki + quad) ^ (l16 & 7)) * 8));
        acc0 = __builtin_amdgcn_mfma_f32_16x16x32_bf16(af, breg[ki][0], acc0, 0, 0, 0);
        acc1 = __builtin_amdgcn_mfma_f32_16x16x32_bf16(af, breg[ki][1], acc1, 0, 0, 0);
      }
      // D layout: row(t)=quad*4+i, col(n)=l16 (m89-verified)
      float* ub = &ubuf[s & 1][0][0];
#pragma unroll
      for (int i = 0; i < 4; ++i) {
        ub[(quad * 4 + i) * 201 + lnb + l16] = acc0[i];
        ub[(quad * 4 + i) * 201 + lnb + 16 + l16] = acc1[i];
      }
      WAITL();
      __builtin_amdgcn_s_barrier();
    }
  } else if (wave == 6) {
    // ---------------- x producer role ----------------
    const float* xsrc = x + (size_t)b * 512;
    float4 xr[32];
#define XISSUE(BLK)                                                         \
  _Pragma("unroll") for (int v = 0; v < 32; ++v) {                          \
    int r = v >> 1;                                                         \
    int fq = (v & 1) * 64 + lane;                                           \
    xr[v] = *(const float4*)(xsrc + (size_t)((BLK) * 16 + r) * 16384 + fq * 4); \
  }
#define XWRITE(BUF)                                                         \
  _Pragma("unroll") for (int v = 0; v < 32; ++v) {                          \
    int r = v >> 1;                                                         \
    int fq = (v & 1) * 64 + lane;                                           \
    float4 w4 = xr[v];                                                      \
    bf16x4 o = {(__bf16)w4.x, (__bf16)w4.y, (__bf16)w4.z, (__bf16)w4.w};    \
    *(bf16x4*)((__bf16*)xbuf[BUF] + r * 512 + (((fq >> 1) ^ (r & 7)) * 8) + \
               (fq & 1) * 4) = o;                                           \
  }
    XISSUE(0);
    WAITV(0);
    XWRITE(0);
    XISSUE(1);  // stage-ahead: latency hidden under stage 0
    WAITL();
    __builtin_amdgcn_s_barrier();  // prime
    for (int s = 0; s < 64; ++s) {
      if (s + 1 < 64) {
        WAITV(0);            // regs for x-tile s+1 landed (issued last stage)
        XWRITE((s + 1) & 1); // gemm reads xbuf[s&1] concurrently
      }
      if (s + 2 < 64) XISSUE(s + 2);
      WAITL();
      __builtin_amdgcn_s_barrier();
    }
#undef XISSUE
#undef XWRITE
  } else {
    // ---------------- scan role ----------------
    const int ob = b * 512 + j0 + lane;
    const float L2E = 1.4426950408889634f;
    const float vf = wc[j0 + lane], vr = wc[512 + j0 + lane];
    const float bfv = bias[j0 + lane], brv = bias[512 + j0 + lane];
    const float wf2 = -vf * L2E;   // sigmoid via exp2: e = 2^(wf2*c + k2)
    const float wr2 = -vr * L2E;
    float c = c0[ob];
    float* op = out + ob;
    const float* xs2 = x + ob;
    float xa[16], xb2[16];
#define XLOAD(BANK, BLK)                                                    \
  _Pragma("unroll") for (int i = 0; i < 16; ++i) BANK[i] =                  \
      xs2[(size_t)((BLK) * 16 + i) * 16384];
#define CONSUME(S1, BANK)                                                   \
  {                                                                         \
    const float* ub = &ubuf[(S1) & 1][0][0];                                \
    float u0a[16], k2a[16], cc[16];                                         \
    /* pass0: loads + off-chain precompute (ILP-full) */                    \
    _Pragma("unroll") for (int i = 0; i < 16; ++i) {                        \
      u0a[i] = ub[i * 201 + lane];                                          \
      float u1 = ub[i * 201 + 64 + lane];                                   \
      k2a[i] = -(u1 + bfv) * L2E;                                           \
    }                                                                       \
    /* pass1: minimal serial c-chain: fma -> exp -> add -> rcp -> fma */    \
    _Pragma("unroll") for (int i = 0; i < 16; ++i) {                        \
      float t = __builtin_fmaf(wf2, c, k2a[i]);                             \
      float e;                                                              \
      asm("v_exp_f32 %0, %1" : "=v"(e) : "v"(t));                           \
      float fr = __builtin_amdgcn_rcpf(1.f + e);                            \
      c = __builtin_fmaf(c - u0a[i], fr, u0a[i]);                           \
      cc[i] = c;                                                            \
    }                                                                       \
    /* pass2: r/tanh/h for all 16 steps, independent across i */            \
    _Pragma("unroll") for (int i = 0; i < 16; ++i) {                        \
      float ci = cc[i];                                                     \
      float u2 = ub[i * 201 + 128 + lane];                                  \
      float t2 = __builtin_fmaf(wr2, ci, -(u2 + brv) * L2E);                \
      float e2;                                                             \
      asm("v_exp_f32 %0, %1" : "=v"(e2) : "v"(t2));                         \
      float rg = __builtin_amdgcn_rcpf(1.f + e2);                           \
      float t3 = __builtin_fabsf(ci) * (-2.f * L2E);                        \
      float e3;                                                             \
      asm("v_exp_f32 %0, %1" : "=v"(e3) : "v"(t3));                         \
      float gg = (1.f - e3) * __builtin_amdgcn_rcpf(1.f + e3);              \
      gg = __builtin_copysignf(gg, ci);                                     \
      float xsc = BANK[i] * 1.7320508075688772f;                            \
      float h = __builtin_fmaf(rg, gg - xsc, xsc);                          \
      op[(size_t)((S1) * 16 + i) * 16384] = h;                              \
    }                                                                       \
  }
    __builtin_amdgcn_s_barrier();  // prime
    // stage 0: issue x(0) only (nothing to consume yet)
    XLOAD(xa, 0);
    __builtin_amdgcn_s_barrier();
    // stages 1..62 in ping-pong pairs; stage s issues XL(s)->bank[s&1],
    // WAITV(16) retires XL(s-1)+stores(s-2), consumes u(s-1)+x(s-1).
    for (int sp = 1; sp < 63; sp += 2) {
      XLOAD(xb2, sp);
      WAITV(16);
      CONSUME(sp - 1, xa);
      __builtin_amdgcn_s_barrier();
      XLOAD(xa, sp + 1);
      WAITV(16);
      CONSUME(sp, xb2);
      __builtin_amdgcn_s_barrier();
    }
    // stage 63
    XLOAD(xb2, 63);
    WAITV(16);
    CONSUME(62, xa);
    __builtin_amdgcn_s_barrier();
    // tail: consume u(63) (written before the last barrier)
    WAITV(16);
    CONSUME(63, xb2);
    out[(size_t)16777216 + ob] = c;  // c_last
#undef XLOAD
#undef CONSUME
  }
}

extern "C" void kernel_launch(void* const* d_in, const int* in_sizes, int n_in,
                              void* d_out, int out_size, void* d_ws, size_t ws_size,
                              hipStream_t stream) {
  const float* x = (const float*)d_in[0];     // (1024,32,512) fp32
  const float* w = (const float*)d_in[1];     // (512,1536)    fp32
  const float* wc = (const float*)d_in[2];    // (1024,)       fp32
  const float* bias = (const float*)d_in[3];  // (1024,)       fp32
  const float* c0 = (const float*)d_in[4];    // (32,512)      fp32
  float* out = (float*)d_out;                 // h (L,B,d) | c_last (B,d)

  char* ws = (char*)d_ws;
  __bf16* wt = (__bf16*)ws;  // 1,572,864 B

  cvt_w<<<dim3(8, 24), 256, 0, stream>>>(w, wt);
  fused_kernel<<<256, 512, 0, stream>>>(x, wt, wc, bias, c0, out);
}